// Round 1
// baseline (700.216 us; speedup 1.0000x reference)
//
#include <hip/hip_runtime.h>
#include <hip/hip_bf16.h>

// Problem constants (B,T,D fixed by setup_inputs)
#define B_  8
#define T_  4096
#define D_  1024
#define M_  (B_*T_)   // 32768 rows
#define N_  (2*D_)    // 2048 cols of projection
#define K_  D_        // 1024
#define NC_ 32        // chunks over T
#define C_  (T_/NC_)  // 128 steps per chunk

typedef short bf16x8 __attribute__((ext_vector_type(8)));
typedef float f32x4  __attribute__((ext_vector_type(4)));

__device__ __forceinline__ unsigned short f2bf(float f) {
  union { float f; unsigned int u; } v; v.f = f;
  unsigned int r = (v.u + 0x7fffu + ((v.u >> 16) & 1u)) >> 16;
  return (unsigned short)r;
}

__device__ __forceinline__ float sigm(float x) {
  return 1.0f / (1.0f + __expf(-x));
}

// async global->LDS, 16B per lane; lds base must be wave-uniform
__device__ __forceinline__ void async16(const void* g, void* l) {
  __builtin_amdgcn_global_load_lds((const __attribute__((address_space(1))) void*)g,
                                   (__attribute__((address_space(3))) void*)l,
                                   16, 0, 0);
}

// ---------------- cast kernels ----------------
__global__ void cast_x_kernel(const float* __restrict__ x, unsigned short* __restrict__ xb) {
  const long n4 = (long)M_ * K_ / 4;
  long i = (long)blockIdx.x * blockDim.x + threadIdx.x;
  const long stride = (long)gridDim.x * blockDim.x;
  for (; i < n4; i += stride) {
    float4 v = ((const float4*)x)[i];
    ushort4 o;
    o.x = f2bf(v.x); o.y = f2bf(v.y); o.z = f2bf(v.z); o.w = f2bf(v.w);
    ((ushort4*)xb)[i] = o;
  }
}

// W [K, N] fp32 -> Wt [N, K] bf16 (tiled transpose)
__global__ void cast_wt_kernel(const float* __restrict__ W, unsigned short* __restrict__ Wt) {
  __shared__ float tile[32][33];
  const int n0 = blockIdx.x * 32, k0 = blockIdx.y * 32;
  const int tx = threadIdx.x, ty = threadIdx.y; // (32, 8)
  for (int i = 0; i < 32; i += 8)
    tile[ty + i][tx] = W[(size_t)(k0 + ty + i) * N_ + n0 + tx];
  __syncthreads();
  for (int i = 0; i < 32; i += 8)
    Wt[(size_t)(n0 + ty + i) * K_ + k0 + tx] = f2bf(tile[tx][ty + i]);
}

// ---------------- GEMM: P = Xb @ WtT + bias, fused gate epilogue ----------------
// A: [M,K] bf16 row-major.  Bt: [N,K] bf16 row-major (i.e. W^T).
// epilogue: n <  D_ : G[m, n]       = g(val)     (g(x)= x>=0? x+0.5 : sigmoid(x))
//           n >= D_ : S[m, n - D_]  = sigmoid(val)
#define BM 128
#define BN 128
#define BK 64

__global__ __launch_bounds__(256, 2) void gemm_kernel(
    const unsigned short* __restrict__ A,
    const unsigned short* __restrict__ Bt,
    const float* __restrict__ bias,
    float* __restrict__ Sout,
    float* __restrict__ Gout) {
  __shared__ unsigned short lds[2 * BM * BK];
  unsigned short* As = lds;
  unsigned short* Bs = lds + BM * BK;

  const int tid  = threadIdx.x;
  const int wave = tid >> 6;
  const int lane = tid & 63;
  const int m0 = blockIdx.y * BM;
  const int n0 = blockIdx.x * BN;
  const int wm = wave >> 1;        // 0..1
  const int wn = wave & 1;         // 0..1
  const int n15  = lane & 15;
  const int quad = lane >> 4;

  f32x4 acc[4][4] = {};

  for (int k0 = 0; k0 < K_; k0 += BK) {
    // stage A tile [BM][BK] and B tile [BN][BK]; 16 segments of 512 elems each
    for (int i = 0; i < 4; ++i) {
      const int seg  = wave * 4 + i;           // 0..15
      const int eoff = seg * 512 + lane * 8;   // element index in tile
      const int row  = eoff >> 6;              // /BK
      const int col  = eoff & 63;
      async16(A  + (size_t)(m0 + row) * K_ + k0 + col, As + seg * 512);
      async16(Bt + (size_t)(n0 + row) * K_ + k0 + col, Bs + seg * 512);
    }
    __syncthreads();  // drains vmcnt (global_load_lds) per compiler barrier semantics

    for (int kk = 0; kk < 2; ++kk) {
      const int kbase = kk * 32 + quad * 8;
      bf16x8 af[4], bfr[4];
      for (int i = 0; i < 4; ++i)
        af[i] = *(const bf16x8*)(As + (size_t)(wm * 64 + i * 16 + n15) * BK + kbase);
      for (int j = 0; j < 4; ++j)
        bfr[j] = *(const bf16x8*)(Bs + (size_t)(wn * 64 + j * 16 + n15) * BK + kbase);
      for (int i = 0; i < 4; ++i)
        for (int j = 0; j < 4; ++j)
          acc[i][j] = __builtin_amdgcn_mfma_f32_16x16x32_bf16(af[i], bfr[j], acc[i][j], 0, 0, 0);
    }
    __syncthreads();
  }

  // epilogue; n-range of a block is entirely in one half (BN=128 divides D_)
  const bool is_k = (n0 >= D_);
  float* __restrict__ dst = is_k ? Sout : Gout;
  for (int j = 0; j < 4; ++j) {
    const int n = n0 + wn * 64 + j * 16 + n15;
    const float bv = bias[n];
    const int d = is_k ? (n - D_) : n;
    for (int i = 0; i < 4; ++i) {
      const int mbase = m0 + wm * 64 + i * 16 + quad * 4;
      for (int r = 0; r < 4; ++r) {
        const float val = acc[i][j][r] + bv;
        float o;
        if (is_k) o = sigm(val);                              // z = sigmoid(k)
        else      o = (val >= 0.0f) ? (val + 0.5f) : sigm(val); // g(h_tilde)
        dst[(size_t)(mbase + r) * D_ + d] = o;
      }
    }
  }
}

// ---------------- pass 1: per-chunk aggregates (A = prod a, V = local scan end) ----------------
__global__ void chunk_agg_kernel(const float* __restrict__ S, const float* __restrict__ G,
                                 float* __restrict__ AggA, float* __restrict__ AggV) {
  const int d = blockIdx.x * 256 + threadIdx.x;
  const int c = blockIdx.y;
  const int b = blockIdx.z;
  size_t base = ((size_t)b * T_ + (size_t)c * C_) * D_ + d;
  float Aa = 1.0f, V = 0.0f;
  for (int t = 0; t < C_; ++t) {
    const float s = S[base];
    const float g = G[base];
    const float a = 1.0f - s;
    V = fmaf(a, V, s * g);
    Aa *= a;
    base += D_;
  }
  const int idx = (b * NC_ + c) * D_ + d;
  AggA[idx] = Aa;
  AggV[idx] = V;
}

// ---------------- pass 2: exclusive scan over chunk aggregates ----------------
__global__ void chunk_scan_kernel(const float* __restrict__ AggA, const float* __restrict__ AggV,
                                  float* __restrict__ H0) {
  const int d = blockIdx.x * 256 + threadIdx.x;
  const int b = blockIdx.y;
  float h = 0.0f;
  for (int c = 0; c < NC_; ++c) {
    const int idx = (b * NC_ + c) * D_ + d;
    H0[idx] = h;
    h = fmaf(AggA[idx], h, AggV[idx]);
  }
}

// ---------------- pass 3: replay scan + residual + LayerNorm fused ----------------
__global__ __launch_bounds__(1024, 1) void scan_ln_kernel(
    const float* __restrict__ S, const float* __restrict__ G,
    const float* __restrict__ x, const float* __restrict__ H0,
    const float* __restrict__ gamma, const float* __restrict__ beta,
    float* __restrict__ out) {
  const int d = threadIdx.x;         // 0..1023 (full D row)
  const int c = blockIdx.x;
  const int b = blockIdx.y;
  const int wid = d >> 6, lane = d & 63;

  __shared__ float redS[16], redQ[16], bc[2];

  float h = H0[(b * NC_ + c) * D_ + d];
  const float gam = gamma[d], bet = beta[d];
  size_t base = ((size_t)b * T_ + (size_t)c * C_) * D_ + d;

  for (int t = 0; t < C_; ++t) {
    const float s = S[base];
    const float g = G[base];
    const float xv = x[base];
    h = fmaf(s, g - h, h);           // (1-s)*h + s*g
    const float y = xv + h;

    float sy = y, sq = y * y;
    for (int o = 32; o > 0; o >>= 1) {
      sy += __shfl_down(sy, o);
      sq += __shfl_down(sq, o);
    }
    if (lane == 0) { redS[wid] = sy; redQ[wid] = sq; }
    __syncthreads();
    if (wid == 0) {
      float ps = (lane < 16) ? redS[lane] : 0.0f;
      float pq = (lane < 16) ? redQ[lane] : 0.0f;
      for (int o = 8; o > 0; o >>= 1) {
        ps += __shfl_down(ps, o);
        pq += __shfl_down(pq, o);
      }
      if (lane == 0) {
        const float mu  = ps * (1.0f / D_);
        const float var = pq * (1.0f / D_) - mu * mu;
        bc[0] = mu;
        bc[1] = rsqrtf(var + 1e-6f);
      }
    }
    __syncthreads();
    out[base] = (y - bc[0]) * bc[1] * gam + bet;
    base += D_;
  }
}

// ---------------- launcher ----------------
extern "C" void kernel_launch(void* const* d_in, const int* in_sizes, int n_in,
                              void* d_out, int out_size, void* d_ws, size_t ws_size,
                              hipStream_t stream) {
  const float* x     = (const float*)d_in[0];
  const float* W     = (const float*)d_in[1];
  const float* bias  = (const float*)d_in[2];
  const float* gamma = (const float*)d_in[3];
  const float* beta  = (const float*)d_in[4];
  float* out = (float*)d_out;

  char* ws = (char*)d_ws;
  unsigned short* Wt = (unsigned short*)ws;            ws += (size_t)N_ * K_ * 2;       // 4 MB
  unsigned short* Xb = (unsigned short*)ws;            ws += (size_t)M_ * K_ * 2;       // 64 MB
  float* S    = (float*)ws;                            ws += (size_t)M_ * D_ * 4;       // 128 MB
  float* G    = (float*)ws;                            ws += (size_t)M_ * D_ * 4;       // 128 MB
  float* AggA = (float*)ws;                            ws += (size_t)B_ * NC_ * D_ * 4; // 1 MB
  float* AggV = (float*)ws;                            ws += (size_t)B_ * NC_ * D_ * 4; // 1 MB
  float* H0   = (float*)ws;                            ws += (size_t)B_ * NC_ * D_ * 4; // 1 MB

  cast_x_kernel<<<4096, 256, 0, stream>>>(x, Xb);
  cast_wt_kernel<<<dim3(N_ / 32, K_ / 32), dim3(32, 8), 0, stream>>>(W, Wt);
  gemm_kernel<<<dim3(N_ / BN, M_ / BM), 256, 0, stream>>>(Xb, Wt, bias, S, G);
  chunk_agg_kernel<<<dim3(D_ / 256, NC_, B_), 256, 0, stream>>>(S, G, AggA, AggV);
  chunk_scan_kernel<<<dim3(D_ / 256, B_), 256, 0, stream>>>(AggA, AggV, H0);
  scan_ln_kernel<<<dim3(NC_, B_), 1024, 0, stream>>>(S, G, x, H0, gamma, beta, out);
}

// Round 3
// 474.829 us; speedup vs baseline: 1.4747x; 1.4747x over previous
//
#include <hip/hip_runtime.h>
#include <hip/hip_bf16.h>

#define B_  8
#define T_  4096
#define D_  1024
#define M_  (B_*T_)   // 32768
#define N_  (2*D_)    // 2048
#define K_  D_        // 1024
#define NC_ 32        // chunks over T
#define C_  (T_/NC_)  // 128 steps per chunk

typedef short bf16x8 __attribute__((ext_vector_type(8)));
typedef float f32x4  __attribute__((ext_vector_type(4)));

__device__ __forceinline__ unsigned short f2bf(float f) {
  union { float f; unsigned int u; } v; v.f = f;
  unsigned int r = (v.u + 0x7fffu + ((v.u >> 16) & 1u)) >> 16;
  return (unsigned short)r;
}

__device__ __forceinline__ float bf2f(unsigned short u) {
  union { unsigned int u; float f; } v; v.u = ((unsigned int)u) << 16; return v.f;
}

__device__ __forceinline__ float sigm(float x) {
  return 1.0f / (1.0f + __expf(-x));
}

// async global->LDS, 16B per lane; lds base must be wave-uniform
__device__ __forceinline__ void async16(const void* g, void* l) {
  __builtin_amdgcn_global_load_lds((const __attribute__((address_space(1))) void*)g,
                                   (__attribute__((address_space(3))) void*)l,
                                   16, 0, 0);
}

// ---------------- cast kernels ----------------
__global__ void cast_x_kernel(const float* __restrict__ x, unsigned short* __restrict__ xb) {
  const long n4 = (long)M_ * K_ / 4;
  long i = (long)blockIdx.x * blockDim.x + threadIdx.x;
  const long stride = (long)gridDim.x * blockDim.x;
  for (; i < n4; i += stride) {
    float4 v = ((const float4*)x)[i];
    ushort4 o;
    o.x = f2bf(v.x); o.y = f2bf(v.y); o.z = f2bf(v.z); o.w = f2bf(v.w);
    ((ushort4*)xb)[i] = o;
  }
}

// W [K, N] fp32 -> Wt [N, K] bf16 (tiled transpose)
__global__ void cast_wt_kernel(const float* __restrict__ W, unsigned short* __restrict__ Wt) {
  __shared__ float tile[32][33];
  const int n0 = blockIdx.x * 32, k0 = blockIdx.y * 32;
  const int tx = threadIdx.x, ty = threadIdx.y; // (32, 8)
  for (int i = 0; i < 32; i += 8)
    tile[ty + i][tx] = W[(size_t)(k0 + ty + i) * N_ + n0 + tx];
  __syncthreads();
  for (int i = 0; i < 32; i += 8)
    Wt[(size_t)(n0 + ty + i) * K_ + k0 + tx] = f2bf(tile[tx][ty + i]);
}

// ---------------- GEMM: P = Xb @ Wt^T + bias, fused gate epilogue, bf16 out ----------------
#define BM 128
#define BN 128
#define BK 64

__global__ __launch_bounds__(256, 3) void gemm_kernel(
    const unsigned short* __restrict__ A,
    const unsigned short* __restrict__ Bt,
    const float* __restrict__ bias,
    unsigned short* __restrict__ Sout,
    unsigned short* __restrict__ Gout) {
  __shared__ unsigned short lds[2 * BM * BK];
  unsigned short* As = lds;
  unsigned short* Bs = lds + BM * BK;

  const int tid  = threadIdx.x;
  const int wave = tid >> 6;
  const int lane = tid & 63;

  // XCD-aware swizzle: dispatch id i -> xcd = i&7 (round-robin). Keep all 16
  // n-blocks of one m-tile on the same XCD, consecutive in its queue, so the
  // 256 KB A-tile is HBM-fetched once and L2-resident for its reuse group.
  const int bid   = blockIdx.x;          // 1-D grid of 4096
  const int xcd   = bid & 7;
  const int j     = bid >> 3;            // 0..511
  const int n_idx = j & 15;
  const int m_idx = (j >> 4) * 8 + xcd;  // 0..255
  const int m0 = m_idx * BM;
  const int n0 = n_idx * BN;

  const int wm = wave >> 1;        // 0..1
  const int wn = wave & 1;         // 0..1
  const int n15  = lane & 15;
  const int quad = lane >> 4;

  f32x4 acc[4][4] = {};

  for (int k0 = 0; k0 < K_; k0 += BK) {
    // stage A tile [BM][BK] and B tile [BN][BK]; 16 segments of 512 elems each.
    // XOR swizzle: LDS (row, slot) holds global (row, slot ^ (row&7)) in 8-elem
    // (16B) groups -> fragment reads spread across all 32 banks.
    for (int i = 0; i < 4; ++i) {
      const int seg = wave * 4 + i;            // 0..15
      const int row = seg * 8 + (lane >> 3);   // 0..127
      const int gg  = ((lane & 7) ^ (row & 7)) * 8;
      async16(A  + (size_t)(m0 + row) * K_ + k0 + gg, As + seg * 512);
      async16(Bt + (size_t)(n0 + row) * K_ + k0 + gg, Bs + seg * 512);
    }
    __syncthreads();

    for (int kk = 0; kk < 2; ++kk) {
      const int gg = kk * 4 + quad;            // 16B group index of k-slice
      bf16x8 af[4], bfr[4];
      for (int i = 0; i < 4; ++i) {
        const int row = wm * 64 + i * 16 + n15;
        af[i] = *(const bf16x8*)(As + (size_t)row * BK + ((gg ^ (row & 7)) * 8));
      }
      for (int jj = 0; jj < 4; ++jj) {
        const int row = wn * 64 + jj * 16 + n15;
        bfr[jj] = *(const bf16x8*)(Bs + (size_t)row * BK + ((gg ^ (row & 7)) * 8));
      }
      for (int i = 0; i < 4; ++i)
        for (int jj = 0; jj < 4; ++jj)
          acc[i][jj] = __builtin_amdgcn_mfma_f32_16x16x32_bf16(af[i], bfr[jj], acc[i][jj], 0, 0, 0);
    }
    __syncthreads();
  }

  // epilogue; n-range of a block is entirely in one half (BN divides D_)
  const bool is_k = (n0 >= D_);
  unsigned short* __restrict__ dst = is_k ? Sout : Gout;
  for (int jj = 0; jj < 4; ++jj) {
    const int n = n0 + wn * 64 + jj * 16 + n15;
    const float bv = bias[n];
    const int d = is_k ? (n - D_) : n;
    for (int i = 0; i < 4; ++i) {
      const int mbase = m0 + wm * 64 + i * 16 + quad * 4;
      for (int r = 0; r < 4; ++r) {
        const float val = acc[i][jj][r] + bv;
        float o;
        if (is_k) o = sigm(val);                                // z = sigmoid(k)
        else      o = (val >= 0.0f) ? (val + 0.5f) : sigm(val); // g(h_tilde)
        dst[(size_t)(mbase + r) * D_ + d] = f2bf(o);
      }
    }
  }
}

// ---------------- pass 1: per-chunk aggregates ----------------
__global__ void chunk_agg_kernel(const unsigned short* __restrict__ S,
                                 const unsigned short* __restrict__ G,
                                 float* __restrict__ AggA, float* __restrict__ AggV) {
  const int d = blockIdx.x * 256 + threadIdx.x;
  const int c = blockIdx.y;
  const int b = blockIdx.z;
  size_t base = ((size_t)b * T_ + (size_t)c * C_) * D_ + d;
  float Aa = 1.0f, V = 0.0f;
  for (int t = 0; t < C_; ++t) {
    const float s = bf2f(S[base]);
    const float g = bf2f(G[base]);
    const float a = 1.0f - s;
    V = fmaf(a, V, s * g);
    Aa *= a;
    base += D_;
  }
  const int idx = (b * NC_ + c) * D_ + d;
  AggA[idx] = Aa;
  AggV[idx] = V;
}

// ---------------- pass 2: exclusive scan over chunk aggregates ----------------
__global__ void chunk_scan_kernel(const float* __restrict__ AggA, const float* __restrict__ AggV,
                                  float* __restrict__ H0) {
  const int d = blockIdx.x * 256 + threadIdx.x;
  const int b = blockIdx.y;
  float h = 0.0f;
  for (int c = 0; c < NC_; ++c) {
    const int idx = (b * NC_ + c) * D_ + d;
    H0[idx] = h;
    h = fmaf(AggA[idx], h, AggV[idx]);
  }
}

// ---------------- pass 3: replay scan + residual + LayerNorm, phase-swapped ----------------
// Batches of 16 t: phase 1 (thread = d) scans 16 steps into LDS y-buffer;
// phase 2 (wave = t) does the LN with pure wave shuffles. 2 barriers / 16 t.
__global__ __launch_bounds__(1024, 1) void scan_ln_kernel(
    const unsigned short* __restrict__ S, const unsigned short* __restrict__ G,
    const float* __restrict__ x, const float* __restrict__ H0,
    const float* __restrict__ gamma, const float* __restrict__ beta,
    float* __restrict__ out) {
  __shared__ float yb[16 * 1024];
  const int d = threadIdx.x;         // 0..1023
  const int c = blockIdx.x;
  const int b = blockIdx.y;
  const int wid = d >> 6, lane = d & 63;

  float h = H0[(b * NC_ + c) * D_ + d];
  // LN-phase mapping: this thread covers d2 = lane + 64*j (conflict-free LDS, coalesced stores)
  float gam[16], bet[16];
  for (int j = 0; j < 16; ++j) { gam[j] = gamma[lane + 64 * j]; bet[j] = beta[lane + 64 * j]; }

  size_t base = ((size_t)b * T_ + (size_t)c * C_) * D_ + d;
  for (int batch = 0; batch < 8; ++batch) {
    // phase 1: sequential scan of 16 timesteps, y -> LDS
    for (int tt = 0; tt < 16; ++tt) {
      const size_t idx = base + (size_t)tt * D_;
      const float s = bf2f(S[idx]);
      const float g = bf2f(G[idx]);
      h = fmaf(s, g - h, h);           // (1-s)*h + s*g
      yb[tt * 1024 + d] = x[idx] + h;
    }
    __syncthreads();
    // phase 2: wave `wid` handles local timestep t = wid
    {
      float sy = 0.0f, sq = 0.0f;
      float yv[16];
      for (int j = 0; j < 16; ++j) {
        const float v = yb[wid * 1024 + lane + 64 * j];
        yv[j] = v; sy += v; sq += v * v;
      }
      for (int o = 32; o > 0; o >>= 1) {
        sy += __shfl_down(sy, o);
        sq += __shfl_down(sq, o);
      }
      sy = __shfl(sy, 0); sq = __shfl(sq, 0);
      const float mu   = sy * (1.0f / D_);
      const float rstd = rsqrtf(sq * (1.0f / D_) - mu * mu + 1e-6f);
      const size_t obase = ((size_t)b * T_ + (size_t)c * C_ + (size_t)batch * 16 + wid) * D_;
      for (int j = 0; j < 16; ++j)
        out[obase + lane + 64 * j] = (yv[j] - mu) * rstd * gam[j] + bet[j];
    }
    __syncthreads();
    base += (size_t)16 * D_;
  }
}

// ---------------- launcher ----------------
extern "C" void kernel_launch(void* const* d_in, const int* in_sizes, int n_in,
                              void* d_out, int out_size, void* d_ws, size_t ws_size,
                              hipStream_t stream) {
  const float* x     = (const float*)d_in[0];
  const float* W     = (const float*)d_in[1];
  const float* bias  = (const float*)d_in[2];
  const float* gamma = (const float*)d_in[3];
  const float* beta  = (const float*)d_in[4];
  float* out = (float*)d_out;

  char* ws = (char*)d_ws;
  unsigned short* Wt = (unsigned short*)ws;  ws += (size_t)N_ * K_ * 2;        // 4 MB
  unsigned short* Xb = (unsigned short*)ws;  ws += (size_t)M_ * K_ * 2;        // 64 MB
  unsigned short* S  = (unsigned short*)ws;  ws += (size_t)M_ * D_ * 2;        // 64 MB
  unsigned short* G  = (unsigned short*)ws;  ws += (size_t)M_ * D_ * 2;        // 64 MB
  float* AggA = (float*)ws;                  ws += (size_t)B_ * NC_ * D_ * 4;  // 1 MB
  float* AggV = (float*)ws;                  ws += (size_t)B_ * NC_ * D_ * 4;  // 1 MB
  float* H0   = (float*)ws;                  ws += (size_t)B_ * NC_ * D_ * 4;  // 1 MB

  cast_x_kernel<<<4096, 256, 0, stream>>>(x, Xb);
  cast_wt_kernel<<<dim3(N_ / 32, K_ / 32), dim3(32, 8), 0, stream>>>(W, Wt);
  gemm_kernel<<<4096, 256, 0, stream>>>(Xb, Wt, bias, S, G);
  chunk_agg_kernel<<<dim3(D_ / 256, NC_, B_), 256, 0, stream>>>(S, G, AggA, AggV);
  chunk_scan_kernel<<<dim3(D_ / 256, B_), 256, 0, stream>>>(AggA, AggV, H0);
  scan_ln_kernel<<<dim3(NC_, B_), 1024, 0, stream>>>(S, G, x, H0, gamma, beta, out);
}